// Round 4
// baseline (477.915 us; speedup 1.0000x reference)
//
#include <hip/hip_runtime.h>
#include <math.h>

// BoxDecoder R9: stream-separation probe. Three sequential fill-like kernels
// instead of one mixed kernel.
//
// Evidence: R5 (flat), R6 (coop+nt), R7 (coop+plain), R8 (persistent wave)
// are 4 radically different structures, all ~190-240us kernel-attributable
// (~2.4 TB/s effective) vs the ~85us / 6.3 TB/s floor the harness's own
// fillBufferAligned proves on this buffer. Structure-insensitive limit =>
// memory-system behavior. The one thing all four share: 6 concurrent
// read/write streams chip-wide. The fill has exactly 1 pure write stream.
// Theory: HBM read<->write turnaround + multi-stream mixing is the cap.
//
// R9 splits by output stream, time-separating the traffic:
//   K_box : loc+anchors+cls -> box_tensor (307MB write; the only mixed kernel)
//           wave-autonomous 64-t chunks, wave-private LDS, no barriers (R8
//           store pattern, non-persistent launch which beat persistent).
//   K_mask: cls -> mask (51MB read, 51MB write; single stream pair)
//   K_bidx: index -> bidx (51MB pure write; value = f(index): a true fill)
// Cost: cls read twice (+51MB ~ +8us), +2 launches (~5us). Worth it if
// stream purity buys back ~2x.
//
// Output layout (verified R1-R8): box_tensor [rows,6] f32, then mask [rows],
// then batch_index [rows]; rows = B*A*C, row = t*C + c, t = b*A + a.
// Per t (C==8): 48 floats = 12 float4s; j in [0,12): s=j/3, jm=j%3:
//   jm0 -> (x1,y1,x2,y2) of row 2s
//   jm1 -> (score[2s], 2s+1, x1, y1)
//   jm2 -> (x2, y2, score[2s+1], 2s+2)
// mask/bidx: float4 i covers rows 4i..4i+3, all with t = i>>1 (8 rows/t).
//
// Magic divide m=floor(2^38/A)+1 exact for n<=1.6M (verified R1-R3).

#define MAGIC_SHIFT 38

typedef float vfloat4 __attribute__((ext_vector_type(4)));

// ---- K_bidx: pure write stream, value derived from index ----------------
__global__ __launch_bounds__(256) void bidx_kernel(
    vfloat4* __restrict__ out_bidx4,   // [nT*2]
    unsigned nf4, unsigned A,
    unsigned long long invA)
{
    unsigned g = blockIdx.x * 256u + threadIdx.x;
    if (g >= nf4) return;
    unsigned t = g >> 1;               // 2 float4 per t (C==8)
    unsigned b = (unsigned)(((unsigned long long)t * invA) >> MAGIC_SHIFT);
    float bf = (float)b;
    vfloat4 v = {bf, bf, bf, bf};
    out_bidx4[g] = v;
}

// ---- K_mask: single read stream -> single write stream ------------------
__global__ __launch_bounds__(256) void mask_kernel(
    const vfloat4* __restrict__ cls4,  // [nT*2]
    const float*   __restrict__ th_p,
    vfloat4*       __restrict__ out_mask4, // [nT*2]
    unsigned nf4)
{
    unsigned g = blockIdx.x * 256u + threadIdx.x;
    if (g >= nf4) return;
    float th = *th_p;
    vfloat4 c = cls4[g];
    vfloat4 m;
    m.x = (c.x >= th) ? 1.0f : 0.0f;
    m.y = (c.y >= th) ? 1.0f : 0.0f;
    m.z = (c.z >= th) ? 1.0f : 0.0f;
    m.w = (c.w >= th) ? 1.0f : 0.0f;
    out_mask4[g] = m;
}

// ---- K_box: wave-autonomous decode + coalesced box stores ---------------
__global__ __launch_bounds__(256) void box_kernel(
    const vfloat4* __restrict__ anchors,  // [A]
    const vfloat4* __restrict__ loc,      // [nT]
    const vfloat4* __restrict__ cls4,     // [nT*2]
    const float*   __restrict__ varx_p,
    const float*   __restrict__ vary_p,
    vfloat4*       __restrict__ out_box4, // [nT*12]
    unsigned nChunks, unsigned nT, unsigned A,
    unsigned long long invA)
{
    __shared__ vfloat4 s_box[4][64];
    __shared__ vfloat4 s_cls[4][128];

    const unsigned wv   = threadIdx.x >> 6;
    const unsigned lane = threadIdx.x & 63u;
    vfloat4* sbox  = s_box[wv];
    vfloat4* scls4 = s_cls[wv];
    const float* scls = (const float*)scls4;

    const unsigned ch = blockIdx.x * 4u + wv;   // one chunk per wave
    if (ch >= nChunks) return;
    const unsigned t0     = ch * 64u;
    const unsigned nt_blk = (nT - t0 < 64u) ? (nT - t0) : 64u;

    const float varx = *varx_p;
    const float vary = *vary_p;

    // phase 1: decode own t -> wave-private LDS
    if (lane < nt_blk) {
        unsigned t = t0 + lane;
        unsigned b = (unsigned)(((unsigned long long)t * invA) >> MAGIC_SHIFT);
        unsigned a = t - b * A;
        vfloat4 anc = anchors[a];
        vfloat4 lp  = loc[t];
        float x = fmaf(lp.x * varx, anc.z, anc.x);
        float y = fmaf(lp.y * varx, anc.w, anc.y);
        float w = expf(lp.z * vary) * anc.z;
        float h = expf(lp.w * vary) * anc.w;
        vfloat4 bx;
        bx.x = fmaf(w, -0.5f, x);
        bx.y = fmaf(h, -0.5f, y);
        bx.z = fmaf(w,  0.5f, x);
        bx.w = fmaf(h,  0.5f, y);
        sbox[lane] = bx;
    }
    // phase 2: stage cls (scores embedded in box rows)
    {
        const unsigned cbase = t0 * 2u;
        const unsigned clim  = nt_blk * 2u;
        if (lane < clim)        scls4[lane]       = cls4[cbase + lane];
        if (lane + 64u < clim)  scls4[lane + 64u] = cls4[cbase + lane + 64u];
    }
    // wave-private LDS: in-order DS pipe + explicit drain, no barrier needed
    asm volatile("s_waitcnt lgkmcnt(0)" ::: "memory");

    // phase 3: 12 coalesced box float4 stores
    const unsigned lim  = nt_blk * 12u;
    const unsigned base = t0 * 12u;
#pragma unroll
    for (unsigned k = 0u; k < 12u; ++k) {
        unsigned lg = k * 64u + lane;
        if (lg < lim) {
            unsigned lt = lg / 12u;
            unsigned j  = lg - lt * 12u;
            unsigned s  = j / 3u;
            unsigned jm = j - s * 3u;
            vfloat4 bx  = sbox[lt];
            float sc0 = scls[lt * 8u + 2u * s];
            float sc1 = scls[lt * 8u + 2u * s + 1u];
            float l0  = (float)(2u * s + 1u);
            float l1  = (float)(2u * s + 2u);
            bool j0 = (jm == 0u);
            bool j1 = (jm == 1u);
            vfloat4 r;
            r.x = j0 ? bx.x : (j1 ? sc0  : bx.z);
            r.y = j0 ? bx.y : (j1 ? l0   : bx.w);
            r.z = j0 ? bx.z : (j1 ? bx.x : sc1);
            r.w = j0 ? bx.w : (j1 ? bx.y : l1);
            out_box4[base + lg] = r;
        }
    }
}

// ---------------- Generic fallback (any C with (6C)%4==0) ---------------
__global__ __launch_bounds__(256) void box_decode_kernel(
    const float4* __restrict__ anchors,
    const float4* __restrict__ loc,
    const float*  __restrict__ cls,
    const float*  __restrict__ varx_p,
    const float*  __restrict__ vary_p,
    const float*  __restrict__ th_p,
    vfloat4*      __restrict__ out_box4,
    float*        __restrict__ out_mask,
    float*        __restrict__ out_bidx,
    unsigned n4, unsigned A, unsigned C, unsigned f4_per_t,
    unsigned long long invA, unsigned long long invF)
{
    unsigned g = blockIdx.x * 256u + threadIdx.x;
    if (g >= n4) return;
    unsigned t  = (unsigned)(((unsigned long long)g * invF) >> MAGIC_SHIFT);
    unsigned j  = g - t * f4_per_t;
    unsigned b  = (unsigned)(((unsigned long long)t * invA) >> MAGIC_SHIFT);
    unsigned a  = t - b * A;
    unsigned s  = j / 3u;
    unsigned jm = j - s * 3u;
    float varx = *varx_p, vary = *vary_p, th = *th_p;
    float4 anc = anchors[a];
    float4 lp  = loc[t];
    float x = fmaf(lp.x * varx, anc.z, anc.x);
    float y = fmaf(lp.y * varx, anc.w, anc.y);
    float w = expf(lp.z * vary) * anc.z;
    float h = expf(lp.w * vary) * anc.w;
    float x1 = fmaf(w, -0.5f, x);
    float y1 = fmaf(h, -0.5f, y);
    float x2 = fmaf(w,  0.5f, x);
    float y2 = fmaf(h,  0.5f, y);
    unsigned r0 = t * C + 2u * s;
    float bf = (float)b;
    vfloat4 r;
    if (jm == 0u) {
        r.x = x1; r.y = y1; r.z = x2; r.w = y2;
    } else if (jm == 1u) {
        float sc0 = cls[r0];
        r.x = sc0; r.y = (float)(2u * s + 1u); r.z = x1; r.w = y1;
        out_mask[r0] = (sc0 >= th) ? 1.0f : 0.0f;
        out_bidx[r0] = bf;
    } else {
        float sc1 = cls[r0 + 1u];
        r.x = x2; r.y = y2; r.z = sc1; r.w = (float)(2u * s + 2u);
        out_mask[r0 + 1u] = (sc1 >= th) ? 1.0f : 0.0f;
        out_bidx[r0 + 1u] = bf;
    }
    out_box4[g] = r;
}

extern "C" void kernel_launch(void* const* d_in, const int* in_sizes, int n_in,
                              void* d_out, int out_size, void* d_ws, size_t ws_size,
                              hipStream_t stream) {
    const float* anchors = (const float*)d_in[0];
    const float* loc     = (const float*)d_in[1];
    const float* cls     = (const float*)d_in[2];
    const float* varx_p  = (const float*)d_in[3];
    const float* vary_p  = (const float*)d_in[4];
    const float* th_p    = (const float*)d_in[5];

    unsigned A = (unsigned)(in_sizes[0] / 4);
    unsigned B = (unsigned)((unsigned)in_sizes[1] / (4u * A));
    unsigned C = (unsigned)((unsigned)in_sizes[2] / (A * B));
    unsigned nT = B * A;
    unsigned rows = nT * C;

    float* out_box  = (float*)d_out;
    float* out_mask = out_box + (size_t)rows * 6;
    float* out_bidx = out_mask + rows;

    unsigned long long invA = ((1ULL << MAGIC_SHIFT) / A) + 1ULL;

    if (C == 8u) {
        // K_box: heaviest, mixed read->write
        unsigned nChunks = (nT + 63u) / 64u;
        unsigned nbBox   = (nChunks + 3u) / 4u;
        box_kernel<<<dim3(nbBox), dim3(256), 0, stream>>>(
            (const vfloat4*)anchors, (const vfloat4*)loc, (const vfloat4*)cls,
            varx_p, vary_p,
            (vfloat4*)out_box, nChunks, nT, A, invA);

        // K_mask: one read stream, one write stream
        unsigned nf4 = nT * 2u;
        unsigned nbM = (nf4 + 255u) / 256u;
        mask_kernel<<<dim3(nbM), dim3(256), 0, stream>>>(
            (const vfloat4*)cls, th_p, (vfloat4*)out_mask, nf4);

        // K_bidx: pure write stream (true fill)
        bidx_kernel<<<dim3(nbM), dim3(256), 0, stream>>>(
            (vfloat4*)out_bidx, nf4, A, invA);
    } else {
        unsigned f4_per_t = (6u * C) / 4u;
        unsigned n4 = rows * 6u / 4u;
        unsigned long long invF = ((1ULL << MAGIC_SHIFT) / f4_per_t) + 1ULL;
        unsigned nb = (n4 + 255u) / 256u;
        box_decode_kernel<<<dim3(nb), dim3(256), 0, stream>>>(
            (const float4*)anchors, (const float4*)loc, cls,
            varx_p, vary_p, th_p,
            (vfloat4*)out_box, out_mask, out_bidx,
            n4, A, C, f4_per_t, invA, invF);
    }
}

// Round 5
// 476.058 us; speedup vs baseline: 1.0039x; 1.0039x over previous
//
#include <hip/hip_runtime.h>
#include <math.h>

// BoxDecoder R10: 2-deep software-pipelined, wave-autonomous.
//
// Bracket so far (dur_us): R5 flat 500.9 | R6 coop+nt 451.3 | R7 coop+plain
// 456.3 | R8 persistent 473.0 | R9 stream-split 477.9. All top-5 dispatches
// are the harness's 1.638GB poison fill (~258us @6.3TB/s, fixed). The ONLY
// mechanism not yet bracketed: per-wave latency exposure -- every prior
// variant serializes {issue loads -> ~900cy HBM wait -> stores} per chunk,
// capping store-issue duty cycle. The fill has no load deps (6.3 TB/s at 10%
// occupancy).
//
// R10: per wave, issue chunk k+1's global loads BEFORE consuming chunk k's
// registers; compiler-inserted vmcnt waits then leave next-chunk loads in
// flight under the current chunk's LDS+store phase. mask/bidx are computed
// directly from in-register cls (lane-local, no LDS transpose needed).
// Grid sized for exactly ~4 chunks/wave (1563 blocks -> 6252 waves,
// 25000/6252 = 3.9987, tail imbalance 0.03%; fixes R8's 3.05 stride tail).
//
// Prediction: if latency exposure was the cap, dur_us -> ~370-395.
// If null (445-460), the kernel is at the mixed-traffic roofline and the
// residual is harness fill + restore overhead -> declare roofline.
//
// Output layout (verified R1-R9): box_tensor [rows,6] f32, then mask [rows],
// then batch_index [rows]; rows = B*A*C, row = t*C + c, t = b*A + a.
// Per t (C==8): 48 floats = 12 float4s; j in [0,12): s=j/3, jm=j%3:
//   jm0 -> (x1,y1,x2,y2) of row 2s
//   jm1 -> (score[2s], 2s+1, x1, y1)
//   jm2 -> (x2, y2, score[2s+1], 2s+2)
// mask/bidx: float4 i covers rows 4i..4i+3, all with t = i>>1 (8 rows/t).
//
// Magic divide m=floor(2^38/A)+1 exact for n<=1.6M (verified R1-R3).

#define MAGIC_SHIFT 38

typedef float vfloat4 __attribute__((ext_vector_type(4)));

__device__ __forceinline__ unsigned bdiv(unsigned t, unsigned long long invA) {
    return (unsigned)(((unsigned long long)t * invA) >> MAGIC_SHIFT);
}

// Issue the 4 global loads for chunk ch (all lanes; clamped; no waits here).
__device__ __forceinline__ void ld_chunk(
    unsigned ch, unsigned lane, unsigned nT, unsigned A, unsigned long long invA,
    const vfloat4* __restrict__ anchors, const vfloat4* __restrict__ loc,
    const vfloat4* __restrict__ cls4,
    vfloat4& lp, vfloat4& anc, vfloat4& c0, vfloat4& c1)
{
    unsigned t0 = ch * 64u;
    unsigned t  = t0 + lane;  if (t >= nT) t = nT - 1u;
    unsigned b  = bdiv(t, invA);
    unsigned a  = t - b * A;
    anc = anchors[a];
    lp  = loc[t];
    unsigned nf4 = nT * 2u;
    unsigned i0 = t0 * 2u + lane;        if (i0 >= nf4) i0 = nf4 - 1u;
    unsigned i1 = t0 * 2u + 64u + lane;  if (i1 >= nf4) i1 = nf4 - 1u;
    c0 = cls4[i0];
    c1 = cls4[i1];
}

__global__ __launch_bounds__(256) void box_decode_pipe(
    const vfloat4* __restrict__ anchors,  // [A] (cx, cy, w, h)
    const vfloat4* __restrict__ loc,      // [nT]
    const vfloat4* __restrict__ cls4,     // [nT*2]  (C==8)
    const float*   __restrict__ varx_p,
    const float*   __restrict__ vary_p,
    const float*   __restrict__ th_p,
    vfloat4*       __restrict__ out_box4, // [nT*12]
    vfloat4*       __restrict__ out_mask4,// [nT*2]
    vfloat4*       __restrict__ out_bidx4,// [nT*2]
    unsigned nChunks, unsigned nT, unsigned A,
    unsigned long long invA)
{
    __shared__ vfloat4 s_box[4][64];      // wave-private
    __shared__ vfloat4 s_cls[4][128];     // wave-private

    const unsigned wv   = threadIdx.x >> 6;
    const unsigned lane = threadIdx.x & 63u;
    vfloat4* sbox  = s_box[wv];
    vfloat4* scls4 = s_cls[wv];
    const float* scls = (const float*)scls4;

    const float varx = *varx_p;
    const float vary = *vary_p;
    const float th   = *th_p;

    const unsigned nw = gridDim.x * 4u;
    unsigned ch = blockIdx.x * 4u + wv;
    if (ch >= nChunks) return;

    // ---- prologue: loads for first chunk in flight ----------------------
    vfloat4 lp, anc, c0, c1;
    ld_chunk(ch, lane, nT, A, invA, anchors, loc, cls4, lp, anc, c0, c1);

    for (;;) {
        // ---- prefetch: issue next chunk's loads BEFORE consuming regs ---
        const unsigned ch2 = ch + nw;
        const bool have2 = (ch2 < nChunks);        // wave-uniform
        vfloat4 lp2, anc2, c02, c12;
        if (have2)
            ld_chunk(ch2, lane, nT, A, invA, anchors, loc, cls4,
                     lp2, anc2, c02, c12);

        // ---- process current chunk --------------------------------------
        const unsigned t0     = ch * 64u;
        const unsigned nt_blk = (nT - t0 < 64u) ? (nT - t0) : 64u;
        const unsigned cbase  = t0 * 2u;
        const unsigned clim   = nt_blk * 2u;

        // mask + bidx straight from registers (lane-local, no transpose)
        if (lane < clim) {
            vfloat4 m;
            m.x = (c0.x >= th) ? 1.0f : 0.0f;
            m.y = (c0.y >= th) ? 1.0f : 0.0f;
            m.z = (c0.z >= th) ? 1.0f : 0.0f;
            m.w = (c0.w >= th) ? 1.0f : 0.0f;
            out_mask4[cbase + lane] = m;
            float bf = (float)bdiv(t0 + (lane >> 1), invA);
            vfloat4 bb = {bf, bf, bf, bf};
            out_bidx4[cbase + lane] = bb;
        }
        if (lane + 64u < clim) {
            vfloat4 m;
            m.x = (c1.x >= th) ? 1.0f : 0.0f;
            m.y = (c1.y >= th) ? 1.0f : 0.0f;
            m.z = (c1.z >= th) ? 1.0f : 0.0f;
            m.w = (c1.w >= th) ? 1.0f : 0.0f;
            out_mask4[cbase + 64u + lane] = m;
            float bf = (float)bdiv(t0 + 32u + (lane >> 1), invA);
            vfloat4 bb = {bf, bf, bf, bf};
            out_bidx4[cbase + 64u + lane] = bb;
        }

        // decode own t -> wave-private LDS; stage cls for transpose
        if (lane < nt_blk) {
            float x = fmaf(lp.x * varx, anc.z, anc.x);
            float y = fmaf(lp.y * varx, anc.w, anc.y);
            float w = expf(lp.z * vary) * anc.z;
            float h = expf(lp.w * vary) * anc.w;
            vfloat4 bx;
            bx.x = fmaf(w, -0.5f, x);
            bx.y = fmaf(h, -0.5f, y);
            bx.z = fmaf(w,  0.5f, x);
            bx.w = fmaf(h,  0.5f, y);
            sbox[lane] = bx;
        }
        scls4[lane]       = c0;   // clamped garbage beyond clim never read
        scls4[lane + 64u] = c1;

        // wave-private LDS: in-order DS pipe + explicit drain, no barrier
        asm volatile("s_waitcnt lgkmcnt(0)" ::: "memory");

        // 12 coalesced box float4 stores
        const unsigned lim  = nt_blk * 12u;
        const unsigned base = t0 * 12u;
#pragma unroll
        for (unsigned k = 0u; k < 12u; ++k) {
            unsigned lg = k * 64u + lane;
            if (lg < lim) {
                unsigned lt = lg / 12u;            // const-div -> magic
                unsigned j  = lg - lt * 12u;
                unsigned s  = j / 3u;
                unsigned jm = j - s * 3u;
                vfloat4 bx  = sbox[lt];
                float sc0 = scls[lt * 8u + 2u * s];
                float sc1 = scls[lt * 8u + 2u * s + 1u];
                float l0  = (float)(2u * s + 1u);
                float l1  = (float)(2u * s + 2u);
                bool j0 = (jm == 0u);
                bool j1 = (jm == 1u);
                vfloat4 r;
                r.x = j0 ? bx.x : (j1 ? sc0  : bx.z);
                r.y = j0 ? bx.y : (j1 ? l0   : bx.w);
                r.z = j0 ? bx.z : (j1 ? bx.x : sc1);
                r.w = j0 ? bx.w : (j1 ? bx.y : l1);
                out_box4[base + lg] = r;
            }
        }

        if (!have2) break;
        ch = ch2;
        lp = lp2; anc = anc2; c0 = c02; c1 = c12;  // rotate pipeline regs
    }
}

// ---------------- Generic fallback (any C with (6C)%4==0) ---------------
__global__ __launch_bounds__(256) void box_decode_kernel(
    const float4* __restrict__ anchors,
    const float4* __restrict__ loc,
    const float*  __restrict__ cls,
    const float*  __restrict__ varx_p,
    const float*  __restrict__ vary_p,
    const float*  __restrict__ th_p,
    vfloat4*      __restrict__ out_box4,
    float*        __restrict__ out_mask,
    float*        __restrict__ out_bidx,
    unsigned n4, unsigned A, unsigned C, unsigned f4_per_t,
    unsigned long long invA, unsigned long long invF)
{
    unsigned g = blockIdx.x * 256u + threadIdx.x;
    if (g >= n4) return;
    unsigned t  = (unsigned)(((unsigned long long)g * invF) >> MAGIC_SHIFT);
    unsigned j  = g - t * f4_per_t;
    unsigned b  = (unsigned)(((unsigned long long)t * invA) >> MAGIC_SHIFT);
    unsigned a  = t - b * A;
    unsigned s  = j / 3u;
    unsigned jm = j - s * 3u;
    float varx = *varx_p, vary = *vary_p, th = *th_p;
    float4 anc = anchors[a];
    float4 lp  = loc[t];
    float x = fmaf(lp.x * varx, anc.z, anc.x);
    float y = fmaf(lp.y * varx, anc.w, anc.y);
    float w = expf(lp.z * vary) * anc.z;
    float h = expf(lp.w * vary) * anc.w;
    float x1 = fmaf(w, -0.5f, x);
    float y1 = fmaf(h, -0.5f, y);
    float x2 = fmaf(w,  0.5f, x);
    float y2 = fmaf(h,  0.5f, y);
    unsigned r0 = t * C + 2u * s;
    float bf = (float)b;
    vfloat4 r;
    if (jm == 0u) {
        r.x = x1; r.y = y1; r.z = x2; r.w = y2;
    } else if (jm == 1u) {
        float sc0 = cls[r0];
        r.x = sc0; r.y = (float)(2u * s + 1u); r.z = x1; r.w = y1;
        out_mask[r0] = (sc0 >= th) ? 1.0f : 0.0f;
        out_bidx[r0] = bf;
    } else {
        float sc1 = cls[r0 + 1u];
        r.x = x2; r.y = y2; r.z = sc1; r.w = (float)(2u * s + 2u);
        out_mask[r0 + 1u] = (sc1 >= th) ? 1.0f : 0.0f;
        out_bidx[r0 + 1u] = bf;
    }
    out_box4[g] = r;
}

extern "C" void kernel_launch(void* const* d_in, const int* in_sizes, int n_in,
                              void* d_out, int out_size, void* d_ws, size_t ws_size,
                              hipStream_t stream) {
    const float* anchors = (const float*)d_in[0];
    const float* loc     = (const float*)d_in[1];
    const float* cls     = (const float*)d_in[2];
    const float* varx_p  = (const float*)d_in[3];
    const float* vary_p  = (const float*)d_in[4];
    const float* th_p    = (const float*)d_in[5];

    unsigned A = (unsigned)(in_sizes[0] / 4);
    unsigned B = (unsigned)((unsigned)in_sizes[1] / (4u * A));
    unsigned C = (unsigned)((unsigned)in_sizes[2] / (A * B));
    unsigned nT = B * A;
    unsigned rows = nT * C;

    float* out_box  = (float*)d_out;
    float* out_mask = out_box + (size_t)rows * 6;
    float* out_bidx = out_mask + rows;

    unsigned long long invA = ((1ULL << MAGIC_SHIFT) / A) + 1ULL;

    if (C == 8u) {
        unsigned nChunks = (nT + 63u) / 64u;      // 25,000 for this shape
        // ~4 chunks per wave, near-zero tail imbalance (25000/6252 = 3.9987)
        unsigned nb = (nChunks + 15u) / 16u;
        box_decode_pipe<<<dim3(nb), dim3(256), 0, stream>>>(
            (const vfloat4*)anchors, (const vfloat4*)loc, (const vfloat4*)cls,
            varx_p, vary_p, th_p,
            (vfloat4*)out_box, (vfloat4*)out_mask, (vfloat4*)out_bidx,
            nChunks, nT, A, invA);
    } else {
        unsigned f4_per_t = (6u * C) / 4u;
        unsigned n4 = rows * 6u / 4u;
        unsigned long long invF = ((1ULL << MAGIC_SHIFT) / f4_per_t) + 1ULL;
        unsigned nb = (n4 + 255u) / 256u;
        box_decode_kernel<<<dim3(nb), dim3(256), 0, stream>>>(
            (const float4*)anchors, (const float4*)loc, cls,
            varx_p, vary_p, th_p,
            (vfloat4*)out_box, out_mask, out_bidx,
            n4, A, C, f4_per_t, invA, invF);
    }
}